// Round 1
// baseline (6693.446 us; speedup 1.0000x reference)
//
#include <hip/hip_runtime.h>
#include <cstddef>

// ---------------------------------------------------------------------------
// MoE RQ-VAE forward, fp32 baseline.
// Pipeline: prep_cb (transpose codebook + cnorm) -> 4 encoder GEMMs ->
//           rq_kernel (4-level residual VQ) -> 4 decoder GEMMs.
// All fp32: the indices output (argmin over codebook distances) tolerates no
// flips (threshold 5.1 on values up to 255), so no bf16 in the distance path.
// ---------------------------------------------------------------------------

__device__ __forceinline__ float wave_sum(float v) {
    #pragma unroll
    for (int off = 32; off > 0; off >>= 1)
        v += __shfl_xor(v, off, 64);
    return v;
}

// ---------------------------------------------------------------------------
// Tiled SGEMM: C[M,N] = act(A[M,K] @ W[K,N] + bias).  Row-major everywhere.
// 128x128 block tile, BK=16, 256 threads, 8x8 micro-tile per thread
// (split as 2x2 blocks of 4x4 for conflict-free b128 LDS reads).
// M,N multiples of 128; K multiple of 16 (true for every layer here).
// ---------------------------------------------------------------------------
template<bool RELU>
__global__ __launch_bounds__(256)
void gemm_bias(const float* __restrict__ A, const float* __restrict__ W,
               const float* __restrict__ bias, float* __restrict__ C,
               int M, int K, int N) {
    __shared__ float As[16][132];   // +4 pad: breaks bank conflicts on transpose-store
    __shared__ float Bs[16][128];

    const int t  = threadIdx.x;
    const int tm = t >> 4;          // 0..15
    const int tn = t & 15;          // 0..15
    const int bm = blockIdx.y;
    const int bn = blockIdx.x;

    const int arow = t >> 2;        // 0..63  (and +64)
    const int acol = (t & 3) << 2;  // 0,4,8,12
    const int brow = t >> 5;        // 0..7   (and +8)
    const int bcol = (t & 31) << 2; // 0..124

    const float* Ab = A + (size_t)bm * 128 * K;
    const float* Wb = W + (size_t)bn * 128;

    float acc[8][8];
    #pragma unroll
    for (int i = 0; i < 8; i++)
        #pragma unroll
        for (int j = 0; j < 8; j++) acc[i][j] = 0.f;

    for (int k0 = 0; k0 < K; k0 += 16) {
        float4 a0 = *(const float4*)(Ab + (size_t)arow * K + k0 + acol);
        float4 a1 = *(const float4*)(Ab + (size_t)(arow + 64) * K + k0 + acol);
        float4 b0 = *(const float4*)(Wb + (size_t)(k0 + brow) * N + bcol);
        float4 b1 = *(const float4*)(Wb + (size_t)(k0 + brow + 8) * N + bcol);

        __syncthreads();   // previous iteration's LDS reads complete
        As[acol + 0][arow] = a0.x; As[acol + 1][arow] = a0.y;
        As[acol + 2][arow] = a0.z; As[acol + 3][arow] = a0.w;
        As[acol + 0][arow + 64] = a1.x; As[acol + 1][arow + 64] = a1.y;
        As[acol + 2][arow + 64] = a1.z; As[acol + 3][arow + 64] = a1.w;
        *(float4*)&Bs[brow][bcol]     = b0;
        *(float4*)&Bs[brow + 8][bcol] = b1;
        __syncthreads();

        #pragma unroll
        for (int kk = 0; kk < 16; kk++) {
            float av[8], bv[8];
            *(float4*)&av[0] = *(const float4*)&As[kk][tm * 4];
            *(float4*)&av[4] = *(const float4*)&As[kk][64 + tm * 4];
            *(float4*)&bv[0] = *(const float4*)&Bs[kk][tn * 4];
            *(float4*)&bv[4] = *(const float4*)&Bs[kk][64 + tn * 4];
            #pragma unroll
            for (int i = 0; i < 8; i++)
                #pragma unroll
                for (int j = 0; j < 8; j++)
                    acc[i][j] = fmaf(av[i], bv[j], acc[i][j]);
        }
    }

    const int cbase = bn * 128;
    float bz[8];
    #pragma unroll
    for (int j = 0; j < 4; j++) {
        bz[j]     = bias[cbase + tn * 4 + j];
        bz[j + 4] = bias[cbase + 64 + tn * 4 + j];
    }
    #pragma unroll
    for (int i = 0; i < 8; i++) {
        const int row = bm * 128 + ((i < 4) ? (tm * 4 + i) : (64 + tm * 4 + i - 4));
        float o[8];
        #pragma unroll
        for (int j = 0; j < 8; j++) {
            o[j] = acc[i][j] + bz[j];
            if (RELU) o[j] = fmaxf(o[j], 0.f);
        }
        *(float4*)(C + (size_t)row * N + cbase + tn * 4)      = make_float4(o[0], o[1], o[2], o[3]);
        *(float4*)(C + (size_t)row * N + cbase + 64 + tn * 4) = make_float4(o[4], o[5], o[6], o[7]);
    }
}

// ---------------------------------------------------------------------------
// Codebook prep: cbT[l][e][d][k] = cb[l][e][k][d]; cnorm[l][e][k] = sum_d cb^2
// One block per (l,e) slab (40 blocks).
// ---------------------------------------------------------------------------
__global__ __launch_bounds__(256)
void prep_cb(const float* __restrict__ cb, float* __restrict__ cbT,
             float* __restrict__ cnorm) {
    const int le = blockIdx.x;              // 0..39
    const float* src = cb  + (size_t)le * 256 * 128;
    float*       dst = cbT + (size_t)le * 128 * 256;
    const int t = threadIdx.x;
    for (int i = 0; i < 128; i++) {
        const int id = i * 256 + t;
        const int k = id >> 7, d = id & 127;
        dst[d * 256 + k] = src[id];
    }
    // cnorm: thread t owns codeword k=t (sequential d order, matching ref scale)
    float s = 0.f;
    const float* row = src + (size_t)t * 128;
    for (int d = 0; d < 128; d++) s = fmaf(row[d], row[d], s);
    cnorm[le * 256 + t] = s;
}

// ---------------------------------------------------------------------------
// Residual quantization: 4 rows per 256-thread block, one wave per row.
// Per level: lane owns codewords 4*lane..4*lane+3, dots via coalesced float4
// loads from cbT with res broadcast from LDS; lexicographic (val,idx) butterfly
// argmin (ties -> lowest index, matching jnp.argmin).
// ---------------------------------------------------------------------------
#define BETA_F 0.001f

__global__ __launch_bounds__(256)
void rq_kernel(const float* __restrict__ z, const int* __restrict__ labels,
               const float* __restrict__ cb,    // [4][10][256][128]
               const float* __restrict__ cbT,   // [4][10][128][256]
               const float* __restrict__ cnorm, // [4][10][256]
               float* __restrict__ out_idx,     // d_out + IDX_OFF (unaligned base ok: scalar)
               float* __restrict__ out_xq,      // d_out + XQ_OFF  (odd offset: scalar stores)
               float* __restrict__ out_loss,    // d_out + LOSS_OFF
               float* __restrict__ xq_ws) {     // aligned copy for decoder input
    __shared__ float res_s[4][128];
    __shared__ float wloss[4];

    const int t = threadIdx.x;
    const int wave = t >> 6, lane = t & 63;
    const int r = blockIdx.x * 4 + wave;
    const int e = labels[r];

    const float2 zv = *(const float2*)(z + (size_t)r * 128 + lane * 2);
    float cur0 = zv.x, cur1 = zv.y;       // this lane's 2 residual entries
    res_s[wave][lane * 2]     = cur0;
    res_s[wave][lane * 2 + 1] = cur1;

    float rnorm = wave_sum(cur0 * cur0 + cur1 * cur1);
    float q0sum = 0.f, q1sum = 0.f, lossacc = 0.f;
    __syncthreads();

    for (int l = 0; l < 4; l++) {
        const float* ct = cbT + (size_t)(l * 10 + e) * 128 * 256 + lane * 4;
        const float* cn = cnorm + (l * 10 + e) * 256;

        float4 acc = make_float4(0.f, 0.f, 0.f, 0.f);
        #pragma unroll 8
        for (int d = 0; d < 128; d++) {
            const float rv = res_s[wave][d];           // broadcast (free)
            const float4 c = *(const float4*)(ct + (size_t)d * 256);
            acc.x = fmaf(rv, c.x, acc.x);
            acc.y = fmaf(rv, c.y, acc.y);
            acc.z = fmaf(rv, c.z, acc.z);
            acc.w = fmaf(rv, c.w, acc.w);
        }
        const float4 cnv = *(const float4*)(cn + lane * 4);
        float dv[4];
        dv[0] = rnorm - 2.f * acc.x + cnv.x;
        dv[1] = rnorm - 2.f * acc.y + cnv.y;
        dv[2] = rnorm - 2.f * acc.z + cnv.z;
        dv[3] = rnorm - 2.f * acc.w + cnv.w;

        int   bi = 4 * lane;
        float bv = dv[0];
        #pragma unroll
        for (int j = 1; j < 4; j++)
            if (dv[j] < bv) { bv = dv[j]; bi = 4 * lane + j; }
        #pragma unroll
        for (int off = 32; off > 0; off >>= 1) {
            const float ov = __shfl_xor(bv, off, 64);
            const int   oi = __shfl_xor(bi, off, 64);
            if (ov < bv || (ov == bv && oi < bi)) { bv = ov; bi = oi; }
        }
        const int idx = bi;

        const float2 qv = *(const float2*)(cb + ((size_t)(l * 10 + e) * 256 + idx) * 128 + lane * 2);
        const float e0 = qv.x - cur0, e1 = qv.y - cur1;
        lossacc += e0 * e0 + e1 * e1;
        cur0 -= qv.x; cur1 -= qv.y;
        q0sum += qv.x; q1sum += qv.y;

        if (lane == 0) out_idx[r * 4 + l] = (float)idx;

        __syncthreads();                 // dot-loop reads done before overwrite
        res_s[wave][lane * 2]     = cur0;
        res_s[wave][lane * 2 + 1] = cur1;
        rnorm = wave_sum(cur0 * cur0 + cur1 * cur1);
        __syncthreads();                 // writes visible before next dot loop
    }

    // x_q = z + (qsum - z), mirrors reference rounding
    const float xq0 = zv.x + (q0sum - zv.x);
    const float xq1 = zv.y + (q1sum - zv.y);
    out_xq[(size_t)r * 128 + lane * 2]     = xq0;   // scalar: d_out region base is odd
    out_xq[(size_t)r * 128 + lane * 2 + 1] = xq1;
    *(float2*)(xq_ws + (size_t)r * 128 + lane * 2) = make_float2(xq0, xq1);

    const float lw = wave_sum(lossacc);
    if (lane == 0) wloss[wave] = lw;
    __syncthreads();
    if (t == 0) {
        const float s = (wloss[0] + wloss[1] + wloss[2] + wloss[3]) *
                        ((1.0f + BETA_F) / (32768.0f * 128.0f));
        atomicAdd(out_loss, s);
    }
}

// ---------------------------------------------------------------------------

extern "C" void kernel_launch(void* const* d_in, const int* in_sizes, int n_in,
                              void* d_out, int out_size, void* d_ws, size_t ws_size,
                              hipStream_t stream) {
    const float* x      = (const float*)d_in[0];
    const int*   labels = (const int*)d_in[1];
    const float* ew[4]  = {(const float*)d_in[2], (const float*)d_in[4],
                           (const float*)d_in[6], (const float*)d_in[8]};
    const float* eb[4]  = {(const float*)d_in[3], (const float*)d_in[5],
                           (const float*)d_in[7], (const float*)d_in[9]};
    const float* dw[4]  = {(const float*)d_in[10], (const float*)d_in[12],
                           (const float*)d_in[14], (const float*)d_in[16]};
    const float* db[4]  = {(const float*)d_in[11], (const float*)d_in[13],
                           (const float*)d_in[15], (const float*)d_in[17]};
    const float* cb     = (const float*)d_in[18];

    float* out = (float*)d_out;
    const size_t LOSS_OFF = 25165824;   // 32768*768
    const size_t IDX_OFF  = 25165825;
    const size_t XQ_OFF   = 25296897;   // + 32768*4

    // Workspace layout (floats), all 16B-aligned offsets:
    float* ws    = (float*)d_ws;
    float* cbT   = ws;                   // 4*10*128*256 = 1,310,720
    float* cnorm = cbT + 1310720;        // 4*10*256     =    10,240
    float* xq    = cnorm + 10240;        // 32768*128    = 4,194,304
    float* bufA  = xq + 4194304;         // 32768*2048   = 67,108,864
    float* bufB  = bufA + 67108864;      // 32768*1024   = 33,554,432

    const int M = 32768;
    dim3 blk(256);

    prep_cb<<<40, blk, 0, stream>>>(cb, cbT, cnorm);

    // Encoder: x -> bufA(2048) -> bufB(1024) -> bufA(512) -> bufB(z,128)
    gemm_bias<true ><<<dim3(16, 256), blk, 0, stream>>>(x,    ew[0], eb[0], bufA, M,  768, 2048);
    gemm_bias<true ><<<dim3( 8, 256), blk, 0, stream>>>(bufA, ew[1], eb[1], bufB, M, 2048, 1024);
    gemm_bias<true ><<<dim3( 4, 256), blk, 0, stream>>>(bufB, ew[2], eb[2], bufA, M, 1024,  512);
    gemm_bias<false><<<dim3( 1, 256), blk, 0, stream>>>(bufA, ew[3], eb[3], bufB, M,  512,  128);

    hipMemsetAsync((char*)d_out + LOSS_OFF * 4, 0, 4, stream);

    rq_kernel<<<8192, blk, 0, stream>>>(bufB, labels, cb, cbT, cnorm,
                                        out + IDX_OFF, out + XQ_OFF, out + LOSS_OFF, xq);

    // Decoder: xq -> bufA(512) -> bufB(1024) -> bufA(2048) -> out(768)
    gemm_bias<true ><<<dim3( 4, 256), blk, 0, stream>>>(xq,   dw[0], db[0], bufA, M,  128,  512);
    gemm_bias<true ><<<dim3( 8, 256), blk, 0, stream>>>(bufA, dw[1], db[1], bufB, M,  512, 1024);
    gemm_bias<true ><<<dim3(16, 256), blk, 0, stream>>>(bufB, dw[2], db[2], bufA, M, 1024, 2048);
    gemm_bias<false><<<dim3( 6, 256), blk, 0, stream>>>(bufA, dw[3], db[3], out,  M, 2048,  768);
}

// Round 2
// 2690.154 us; speedup vs baseline: 2.4881x; 2.4881x over previous
//
#include <hip/hip_runtime.h>
#include <cstdint>
#include <cstddef>

// ---------------------------------------------------------------------------
// MoE RQ-VAE forward, MFMA version.
//   Encoder: f16 two-term split (lo plane pre-scaled x2048, dual accumulator,
//            3 MFMA products) -> ~2^-21 per-product error, fp32-grade z.
//   Decoder: plain bf16 MFMA (output threshold is loose; xq itself stays fp32).
//   RQ stage: unchanged fp32 (verified round 1), now also emits bf16 xq plane.
// GEMM core: 128x128 tile, BK=32, global_load_lds width-16 staging with XOR
// chunk swizzle (2-way LDS conflicts only), 16x16x32 MFMA, 4 waves x 64x64.
// ---------------------------------------------------------------------------

typedef _Float16 half8  __attribute__((ext_vector_type(8)));
typedef short    short8 __attribute__((ext_vector_type(8)));
typedef float    f32x4  __attribute__((ext_vector_type(4)));

__device__ __forceinline__ uint16_t f32_to_bf16(float v) {
    uint32_t u = __float_as_uint(v);
    u += 0x7fff + ((u >> 16) & 1);
    return (uint16_t)(u >> 16);
}
__device__ __forceinline__ uint16_t f32_to_f16_bits(float v) {
    _Float16 h = (_Float16)v;
    return __builtin_bit_cast(uint16_t, h);
}

__device__ __forceinline__ float wave_sum(float v) {
    #pragma unroll
    for (int off = 32; off > 0; off >>= 1)
        v += __shfl_xor(v, off, 64);
    return v;
}

#define GLOAD_LDS16(g, l)                                                      \
    __builtin_amdgcn_global_load_lds(                                          \
        (const __attribute__((address_space(1))) void*)(g),                    \
        (__attribute__((address_space(3))) void*)(l), 16, 0, 0)

template<bool F16> struct VecT        { using type = half8;  };
template<>         struct VecT<false> { using type = short8; };

__device__ __forceinline__ f32x4 mfma16(half8 a, half8 b, f32x4 c) {
    return __builtin_amdgcn_mfma_f32_16x16x32_f16(a, b, c, 0, 0, 0);
}
__device__ __forceinline__ f32x4 mfma16(short8 a, short8 b, f32x4 c) {
    return __builtin_amdgcn_mfma_f32_16x16x32_bf16(a, b, c, 0, 0, 0);
}

// ---------------------------------------------------------------------------
// MFMA GEMM: C[M,N] = act(A[M,K] @ W[K,N] + bias)
//   A: NPL planes of u16 (plane stride M*K elems), Wt: NPL planes [N][K].
//   CORR: dual-accumulator split-f16 correction (requires NPL=2).
//   OUT: 0 = fp32 Cf; 1 = f16 hi/lo planes C0/C1 (lo x2048); 2 = bf16 C0.
// ---------------------------------------------------------------------------
template<int NPL, bool ISF16, bool CORR, bool RELU, int OUT>
__global__ __launch_bounds__(256)
void gemm_mfma(const uint16_t* __restrict__ A, const uint16_t* __restrict__ Wt,
               const float* __restrict__ bias,
               float* __restrict__ Cf, uint16_t* __restrict__ C0,
               uint16_t* __restrict__ C1, int M, int K, int N) {
    using vec8 = typename VecT<ISF16>::type;
    __shared__ __align__(16) char lds[NPL * 16384];

    const int t    = threadIdx.x;
    const int lane = t & 63, wave = t >> 6;
    const int wm = wave >> 1, wn = wave & 1;
    const int bm = blockIdx.y, bn = blockIdx.x;

    const size_t planeA = (size_t)M * K;
    const size_t planeB = (size_t)N * K;

    // staging: thread t covers chunk j = t (rows 0..63) and j = 256+t (64..127)
    // LDS chunk j holds global (row r=j>>2, kchunk c=(j&3)^((r>>1)&3))
    const int r0 = t >> 2,        c0 = (t & 3) ^ ((r0 >> 1) & 3);
    const int r1 = 64 + (t >> 2), c1 = (t & 3) ^ ((r1 >> 1) & 3);

    const uint16_t* gA0 = A  + (size_t)(bm * 128 + r0) * K + c0 * 8;
    const uint16_t* gA1 = A  + (size_t)(bm * 128 + r1) * K + c1 * 8;
    const uint16_t* gB0 = Wt + (size_t)(bn * 128 + r0) * K + c0 * 8;
    const uint16_t* gB1 = Wt + (size_t)(bn * 128 + r1) * K + c1 * 8;

    char* ldsA = (char*)lds;
    char* ldsB = (char*)lds + NPL * 8192;
    const int wb = wave * 1024;

    // fragment read offsets (loop-invariant; 2-way-max bank pattern)
    const int l15 = lane & 15, quad = lane >> 4;
    const int cpf = quad ^ ((l15 >> 1) & 3);
    const int aoff = ((wm * 64 + l15) * 4 + cpf) * 16;
    const int boff = ((wn * 64 + l15) * 4 + cpf) * 16;

    f32x4 accM[4][4], accC[4][4];
    #pragma unroll
    for (int mi = 0; mi < 4; ++mi)
        #pragma unroll
        for (int nj = 0; nj < 4; ++nj)
            #pragma unroll
            for (int r = 0; r < 4; ++r) { accM[mi][nj][r] = 0.f; if (CORR) accC[mi][nj][r] = 0.f; }

    for (int kk = 0; kk < K; kk += 32) {
        __syncthreads();
        #pragma unroll
        for (int p = 0; p < NPL; ++p) {
            GLOAD_LDS16(gA0 + (size_t)p * planeA, ldsA + p * 8192 + wb);
            GLOAD_LDS16(gA1 + (size_t)p * planeA, ldsA + p * 8192 + 4096 + wb);
            GLOAD_LDS16(gB0 + (size_t)p * planeB, ldsB + p * 8192 + wb);
            GLOAD_LDS16(gB1 + (size_t)p * planeB, ldsB + p * 8192 + 4096 + wb);
        }
        gA0 += 32; gA1 += 32; gB0 += 32; gB1 += 32;
        __syncthreads();

        vec8 a0[4], b0[4];
        #pragma unroll
        for (int i = 0; i < 4; ++i) {
            a0[i] = *(const vec8*)(ldsA + aoff + i * 1024);
            b0[i] = *(const vec8*)(ldsB + boff + i * 1024);
        }
        #pragma unroll
        for (int mi = 0; mi < 4; ++mi)
            #pragma unroll
            for (int nj = 0; nj < 4; ++nj)
                accM[mi][nj] = mfma16(a0[mi], b0[nj], accM[mi][nj]);

        if (CORR) {
            vec8 b1[4];
            #pragma unroll
            for (int i = 0; i < 4; ++i)
                b1[i] = *(const vec8*)(ldsB + 8192 + boff + i * 1024);
            #pragma unroll
            for (int mi = 0; mi < 4; ++mi)
                #pragma unroll
                for (int nj = 0; nj < 4; ++nj)
                    accC[mi][nj] = mfma16(a0[mi], b1[nj], accC[mi][nj]);
            vec8 a1[4];
            #pragma unroll
            for (int i = 0; i < 4; ++i)
                a1[i] = *(const vec8*)(ldsA + 8192 + aoff + i * 1024);
            #pragma unroll
            for (int mi = 0; mi < 4; ++mi)
                #pragma unroll
                for (int nj = 0; nj < 4; ++nj)
                    accC[mi][nj] = mfma16(a1[mi], b0[nj], accC[mi][nj]);
        }
    }

    if (CORR) {
        #pragma unroll
        for (int mi = 0; mi < 4; ++mi)
            #pragma unroll
            for (int nj = 0; nj < 4; ++nj)
                #pragma unroll
                for (int r = 0; r < 4; ++r)
                    accM[mi][nj][r] += accC[mi][nj][r] * (1.0f / 2048.0f);
    }

    const int colb = bn * 128 + wn * 64 + l15;
    const int rowb = bm * 128 + wm * 64 + quad * 4;
    float bz[4];
    #pragma unroll
    for (int nj = 0; nj < 4; ++nj) bz[nj] = bias[colb + nj * 16];

    #pragma unroll
    for (int mi = 0; mi < 4; ++mi)
        #pragma unroll
        for (int nj = 0; nj < 4; ++nj)
            #pragma unroll
            for (int r = 0; r < 4; ++r) {
                float v = accM[mi][nj][r] + bz[nj];
                if (RELU) v = fmaxf(v, 0.f);
                const size_t o = (size_t)(rowb + mi * 16 + r) * N + colb + nj * 16;
                if (OUT == 0) {
                    Cf[o] = v;
                } else if (OUT == 1) {
                    uint16_t hb = f32_to_f16_bits(v);
                    C0[o] = hb;
                    float hf = (float)__builtin_bit_cast(_Float16, hb);
                    C1[o] = f32_to_f16_bits((v - hf) * 2048.0f);
                } else {
                    C0[o] = f32_to_bf16(v);
                }
            }
}

// ---------------------------------------------------------------------------
// Weight prep: transpose W[K][N] -> planes [N][K].  MODE 0: f16 hi + lo*2048
// (2 planes); MODE 1: bf16 (1 plane).  32x32 LDS tile, 256 threads.
// ---------------------------------------------------------------------------
template<int MODE>
__global__ __launch_bounds__(256)
void prep_w(const float* __restrict__ W, uint16_t* __restrict__ out, int K, int N) {
    __shared__ float tile[32][33];
    const int tx = threadIdx.x & 31, ty = threadIdx.x >> 5;
    const int n0 = blockIdx.x * 32, k0 = blockIdx.y * 32;
    #pragma unroll
    for (int i = 0; i < 4; ++i)
        tile[ty + i * 8][tx] = W[(size_t)(k0 + ty + i * 8) * N + n0 + tx];
    __syncthreads();
    #pragma unroll
    for (int i = 0; i < 4; ++i) {
        float v = tile[tx][ty + i * 8];
        size_t o = (size_t)(n0 + ty + i * 8) * K + k0 + tx;
        if (MODE == 0) {
            uint16_t hb = f32_to_f16_bits(v);
            out[o] = hb;
            float hf = (float)__builtin_bit_cast(_Float16, hb);
            out[o + (size_t)N * K] = f32_to_f16_bits((v - hf) * 2048.0f);
        } else {
            out[o] = f32_to_bf16(v);
        }
    }
}

// x -> f16 hi/lo planes (lo x2048)
__global__ __launch_bounds__(256)
void split_x(const float* __restrict__ x, uint16_t* __restrict__ hi,
             uint16_t* __restrict__ lo, int n4) {
    int i = blockIdx.x * 256 + threadIdx.x;
    const int stride = gridDim.x * 256;
    for (; i < n4; i += stride) {
        float4 v = ((const float4*)x)[i];
        ushort4 h, l;
        uint16_t hb;
        float hf;
        hb = f32_to_f16_bits(v.x); h.x = hb; hf = (float)__builtin_bit_cast(_Float16, hb); l.x = f32_to_f16_bits((v.x - hf) * 2048.f);
        hb = f32_to_f16_bits(v.y); h.y = hb; hf = (float)__builtin_bit_cast(_Float16, hb); l.y = f32_to_f16_bits((v.y - hf) * 2048.f);
        hb = f32_to_f16_bits(v.z); h.z = hb; hf = (float)__builtin_bit_cast(_Float16, hb); l.z = f32_to_f16_bits((v.z - hf) * 2048.f);
        hb = f32_to_f16_bits(v.w); h.w = hb; hf = (float)__builtin_bit_cast(_Float16, hb); l.w = f32_to_f16_bits((v.w - hf) * 2048.f);
        ((ushort4*)hi)[i] = h;
        ((ushort4*)lo)[i] = l;
    }
}

// ---------------------------------------------------------------------------
// Codebook prep (unchanged, verified round 1)
// ---------------------------------------------------------------------------
__global__ __launch_bounds__(256)
void prep_cb(const float* __restrict__ cb, float* __restrict__ cbT,
             float* __restrict__ cnorm) {
    const int le = blockIdx.x;
    const float* src = cb  + (size_t)le * 256 * 128;
    float*       dst = cbT + (size_t)le * 128 * 256;
    const int t = threadIdx.x;
    for (int i = 0; i < 128; i++) {
        const int id = i * 256 + t;
        const int k = id >> 7, d = id & 127;
        dst[d * 256 + k] = src[id];
    }
    float s = 0.f;
    const float* row = src + (size_t)t * 128;
    for (int d = 0; d < 128; d++) s = fmaf(row[d], row[d], s);
    cnorm[le * 256 + t] = s;
}

// ---------------------------------------------------------------------------
// Residual quantization (verified round 1) + bf16 xq plane for decoder
// ---------------------------------------------------------------------------
#define BETA_F 0.001f

__global__ __launch_bounds__(256)
void rq_kernel(const float* __restrict__ z, const int* __restrict__ labels,
               const float* __restrict__ cb, const float* __restrict__ cbT,
               const float* __restrict__ cnorm,
               float* __restrict__ out_idx, float* __restrict__ out_xq,
               float* __restrict__ out_loss, uint16_t* __restrict__ xqbf) {
    __shared__ float res_s[4][128];
    __shared__ float wloss[4];

    const int t = threadIdx.x;
    const int wave = t >> 6, lane = t & 63;
    const int r = blockIdx.x * 4 + wave;
    const int e = labels[r];

    const float2 zv = *(const float2*)(z + (size_t)r * 128 + lane * 2);
    float cur0 = zv.x, cur1 = zv.y;
    res_s[wave][lane * 2]     = cur0;
    res_s[wave][lane * 2 + 1] = cur1;

    float rnorm = wave_sum(cur0 * cur0 + cur1 * cur1);
    float q0sum = 0.f, q1sum = 0.f, lossacc = 0.f;
    __syncthreads();

    for (int l = 0; l < 4; l++) {
        const float* ct = cbT + (size_t)(l * 10 + e) * 128 * 256 + lane * 4;
        const float* cn = cnorm + (l * 10 + e) * 256;

        float4 acc = make_float4(0.f, 0.f, 0.f, 0.f);
        #pragma unroll 8
        for (int d = 0; d < 128; d++) {
            const float rv = res_s[wave][d];
            const float4 c = *(const float4*)(ct + (size_t)d * 256);
            acc.x = fmaf(rv, c.x, acc.x);
            acc.y = fmaf(rv, c.y, acc.y);
            acc.z = fmaf(rv, c.z, acc.z);
            acc.w = fmaf(rv, c.w, acc.w);
        }
        const float4 cnv = *(const float4*)(cn + lane * 4);
        float dv[4];
        dv[0] = rnorm - 2.f * acc.x + cnv.x;
        dv[1] = rnorm - 2.f * acc.y + cnv.y;
        dv[2] = rnorm - 2.f * acc.z + cnv.z;
        dv[3] = rnorm - 2.f * acc.w + cnv.w;

        int   bi = 4 * lane;
        float bv = dv[0];
        #pragma unroll
        for (int j = 1; j < 4; j++)
            if (dv[j] < bv) { bv = dv[j]; bi = 4 * lane + j; }
        #pragma unroll
        for (int off = 32; off > 0; off >>= 1) {
            const float ov = __shfl_xor(bv, off, 64);
            const int   oi = __shfl_xor(bi, off, 64);
            if (ov < bv || (ov == bv && oi < bi)) { bv = ov; bi = oi; }
        }
        const int idx = bi;

        const float2 qv = *(const float2*)(cb + ((size_t)(l * 10 + e) * 256 + idx) * 128 + lane * 2);
        const float e0 = qv.x - cur0, e1 = qv.y - cur1;
        lossacc += e0 * e0 + e1 * e1;
        cur0 -= qv.x; cur1 -= qv.y;
        q0sum += qv.x; q1sum += qv.y;

        if (lane == 0) out_idx[r * 4 + l] = (float)idx;

        __syncthreads();
        res_s[wave][lane * 2]     = cur0;
        res_s[wave][lane * 2 + 1] = cur1;
        rnorm = wave_sum(cur0 * cur0 + cur1 * cur1);
        __syncthreads();
    }

    const float xq0 = zv.x + (q0sum - zv.x);
    const float xq1 = zv.y + (q1sum - zv.y);
    out_xq[(size_t)r * 128 + lane * 2]     = xq0;
    out_xq[(size_t)r * 128 + lane * 2 + 1] = xq1;
    xqbf[(size_t)r * 128 + lane * 2]     = f32_to_bf16(xq0);
    xqbf[(size_t)r * 128 + lane * 2 + 1] = f32_to_bf16(xq1);

    const float lw = wave_sum(lossacc);
    if (lane == 0) wloss[wave] = lw;
    __syncthreads();
    if (t == 0) {
        const float s = (wloss[0] + wloss[1] + wloss[2] + wloss[3]) *
                        ((1.0f + BETA_F) / (32768.0f * 128.0f));
        atomicAdd(out_loss, s);
    }
}

// ---------------------------------------------------------------------------

extern "C" void kernel_launch(void* const* d_in, const int* in_sizes, int n_in,
                              void* d_out, int out_size, void* d_ws, size_t ws_size,
                              hipStream_t stream) {
    const float* x      = (const float*)d_in[0];
    const int*   labels = (const int*)d_in[1];
    const float* ew[4]  = {(const float*)d_in[2], (const float*)d_in[4],
                           (const float*)d_in[6], (const float*)d_in[8]};
    const float* eb[4]  = {(const float*)d_in[3], (const float*)d_in[5],
                           (const float*)d_in[7], (const float*)d_in[9]};
    const float* dw[4]  = {(const float*)d_in[10], (const float*)d_in[12],
                           (const float*)d_in[14], (const float*)d_in[16]};
    const float* db[4]  = {(const float*)d_in[11], (const float*)d_in[13],
                           (const float*)d_in[15], (const float*)d_in[17]};
    const float* cb     = (const float*)d_in[18];

    float* out = (float*)d_out;
    const size_t LOSS_OFF = 25165824;
    const size_t IDX_OFF  = 25165825;
    const size_t XQ_OFF   = 25296897;

    // ---- workspace layout (bytes) ----
    char* W = (char*)d_ws;
    size_t off = 0;
    auto alloc = [&](size_t bytes) { char* p = W + off; off += (bytes + 255) & ~(size_t)255; return p; };
    char*     region1 = alloc(134217728);          // 128 MB
    char*     region2 = alloc(67108864);           // 64 MB
    float*    z       = (float*)alloc(32768ull * 128 * 4);
    uint16_t* xqbf    = (uint16_t*)alloc(32768ull * 128 * 2);
    float*    cbT     = (float*)alloc(4ull * 10 * 128 * 256 * 4);
    float*    cnorm   = (float*)alloc(4ull * 10 * 256 * 4);
    uint16_t* wtE0 = (uint16_t*)alloc(2ull *  768 * 2048 * 2);
    uint16_t* wtE1 = (uint16_t*)alloc(2ull * 2048 * 1024 * 2);
    uint16_t* wtE2 = (uint16_t*)alloc(2ull * 1024 *  512 * 2);
    uint16_t* wtE3 = (uint16_t*)alloc(2ull *  512 *  128 * 2);
    uint16_t* wtD0 = (uint16_t*)alloc(128ull  *  512 * 2);
    uint16_t* wtD1 = (uint16_t*)alloc(512ull  * 1024 * 2);
    uint16_t* wtD2 = (uint16_t*)alloc(1024ull * 2048 * 2);
    uint16_t* wtD3 = (uint16_t*)alloc(2048ull *  768 * 2);

    dim3 blk(256);

    // ---- weight / codebook prep ----
    prep_w<0><<<dim3(2048/32,  768/32), blk, 0, stream>>>(ew[0], wtE0,  768, 2048);
    prep_w<0><<<dim3(1024/32, 2048/32), blk, 0, stream>>>(ew[1], wtE1, 2048, 1024);
    prep_w<0><<<dim3( 512/32, 1024/32), blk, 0, stream>>>(ew[2], wtE2, 1024,  512);
    prep_w<0><<<dim3( 128/32,  512/32), blk, 0, stream>>>(ew[3], wtE3,  512,  128);
    prep_w<1><<<dim3( 512/32,  128/32), blk, 0, stream>>>(dw[0], wtD0,  128,  512);
    prep_w<1><<<dim3(1024/32,  512/32), blk, 0, stream>>>(dw[1], wtD1,  512, 1024);
    prep_w<1><<<dim3(2048/32, 1024/32), blk, 0, stream>>>(dw[2], wtD2, 1024, 2048);
    prep_w<1><<<dim3( 768/32, 2048/32), blk, 0, stream>>>(dw[3], wtD3, 2048,  768);
    prep_cb<<<40, blk, 0, stream>>>(cb, cbT, cnorm);

    // ---- encoder in two M-halves (fits activation planes in ws) ----
    const int MH = 16384;
    for (int half = 0; half < 2; ++half) {
        const float* xh = x + (size_t)half * MH * 768;
        uint16_t* xpl = (uint16_t*)region2;                       // 2 planes 768-wide
        split_x<<<1024, blk, 0, stream>>>(xh, xpl, xpl + (size_t)MH * 768, MH * 768 / 4);

        uint16_t* h1 = (uint16_t*)region1;                        // 2 planes 2048-wide
        gemm_mfma<2, true, true, true, 1><<<dim3(16, 128), blk, 0, stream>>>(
            xpl, wtE0, eb[0], nullptr, h1, h1 + (size_t)MH * 2048, MH, 768, 2048);

        uint16_t* h2 = (uint16_t*)region2;                        // 2 planes 1024-wide
        gemm_mfma<2, true, true, true, 1><<<dim3(8, 128), blk, 0, stream>>>(
            h1, wtE1, eb[1], nullptr, h2, h2 + (size_t)MH * 1024, MH, 2048, 1024);

        uint16_t* h3 = (uint16_t*)region1;                        // 2 planes 512-wide
        gemm_mfma<2, true, true, true, 1><<<dim3(4, 128), blk, 0, stream>>>(
            h2, wtE2, eb[2], nullptr, h3, h3 + (size_t)MH * 512, MH, 1024, 512);

        gemm_mfma<2, true, true, false, 0><<<dim3(1, 128), blk, 0, stream>>>(
            h3, wtE3, eb[3], z + (size_t)half * MH * 128, nullptr, nullptr, MH, 512, 128);
    }

    // ---- residual quantization ----
    hipMemsetAsync((char*)d_out + LOSS_OFF * 4, 0, 4, stream);
    rq_kernel<<<8192, blk, 0, stream>>>(z, labels, cb, cbT, cnorm,
                                        out + IDX_OFF, out + XQ_OFF, out + LOSS_OFF, xqbf);

    // ---- decoder, plain bf16 ----
    const int M = 32768;
    uint16_t* d0 = (uint16_t*)region1;   // 512-wide bf16
    uint16_t* d1 = (uint16_t*)region2;   // 1024-wide bf16
    uint16_t* d2 = (uint16_t*)region1;   // 2048-wide bf16 (d0 dead by then)
    gemm_mfma<1, false, false, true, 2><<<dim3(4, 256), blk, 0, stream>>>(
        xqbf, wtD0, db[0], nullptr, d0, nullptr, M, 128, 512);
    gemm_mfma<1, false, false, true, 2><<<dim3(8, 256), blk, 0, stream>>>(
        d0, wtD1, db[1], nullptr, d1, nullptr, M, 512, 1024);
    gemm_mfma<1, false, false, true, 2><<<dim3(16, 256), blk, 0, stream>>>(
        d1, wtD2, db[2], nullptr, d2, nullptr, M, 1024, 2048);
    gemm_mfma<1, false, false, false, 0><<<dim3(6, 256), blk, 0, stream>>>(
        d2, wtD3, db[3], out, nullptr, nullptr, M, 2048, 768);
}

// Round 3
// 2515.901 us; speedup vs baseline: 2.6605x; 1.0693x over previous
//
#include <hip/hip_runtime.h>
#include <cstdint>
#include <cstddef>

// ---------------------------------------------------------------------------
// MoE RQ-VAE forward.
//   Encoder: f16 two-term split MFMA (3 products) -> fp32-grade z.
//   RQ: rows sorted by expert; per level a fused MFMA kernel computes the
//       64x256 score tile (f16-split, 3 products), argmin, exact fp32 residual
//       update. Codebook read once per 64-row tile instead of once per row.
//   Decoder: plain bf16 MFMA.
// ---------------------------------------------------------------------------

typedef _Float16 half8  __attribute__((ext_vector_type(8)));
typedef short    short8 __attribute__((ext_vector_type(8)));
typedef float    f32x4  __attribute__((ext_vector_type(4)));

__device__ __forceinline__ uint16_t f32_to_bf16(float v) {
    uint32_t u = __float_as_uint(v);
    u += 0x7fff + ((u >> 16) & 1);
    return (uint16_t)(u >> 16);
}
__device__ __forceinline__ uint16_t f32_to_f16_bits(float v) {
    _Float16 h = (_Float16)v;
    return __builtin_bit_cast(uint16_t, h);
}
__device__ __forceinline__ void split16(float v, uint16_t& hb, uint16_t& lb) {
    hb = f32_to_f16_bits(v);
    float hf = (float)__builtin_bit_cast(_Float16, hb);
    lb = f32_to_f16_bits((v - hf) * 2048.0f);
}

__device__ __forceinline__ float wave_sum(float v) {
    #pragma unroll
    for (int off = 32; off > 0; off >>= 1)
        v += __shfl_xor(v, off, 64);
    return v;
}

#define GLOAD_LDS16(g, l)                                                      \
    __builtin_amdgcn_global_load_lds(                                          \
        (const __attribute__((address_space(1))) void*)(g),                    \
        (__attribute__((address_space(3))) void*)(l), 16, 0, 0)

template<bool F16> struct VecT        { using type = half8;  };
template<>         struct VecT<false> { using type = short8; };

__device__ __forceinline__ f32x4 mfma16(half8 a, half8 b, f32x4 c) {
    return __builtin_amdgcn_mfma_f32_16x16x32_f16(a, b, c, 0, 0, 0);
}
__device__ __forceinline__ f32x4 mfma16(short8 a, short8 b, f32x4 c) {
    return __builtin_amdgcn_mfma_f32_16x16x32_bf16(a, b, c, 0, 0, 0);
}

// ---------------------------------------------------------------------------
// MFMA GEMM (unchanged from round 2): C[M,N] = act(A[M,K] @ W[K,N] + bias)
// ---------------------------------------------------------------------------
template<int NPL, bool ISF16, bool CORR, bool RELU, int OUT>
__global__ __launch_bounds__(256)
void gemm_mfma(const uint16_t* __restrict__ A, const uint16_t* __restrict__ Wt,
               const float* __restrict__ bias,
               float* __restrict__ Cf, uint16_t* __restrict__ C0,
               uint16_t* __restrict__ C1, int M, int K, int N) {
    using vec8 = typename VecT<ISF16>::type;
    __shared__ __align__(16) char lds[NPL * 16384];

    const int t    = threadIdx.x;
    const int lane = t & 63, wave = t >> 6;
    const int wm = wave >> 1, wn = wave & 1;
    const int bm = blockIdx.y, bn = blockIdx.x;

    const size_t planeA = (size_t)M * K;
    const size_t planeB = (size_t)N * K;

    const int r0 = t >> 2,        c0 = (t & 3) ^ ((r0 >> 1) & 3);
    const int r1 = 64 + (t >> 2), c1 = (t & 3) ^ ((r1 >> 1) & 3);

    const uint16_t* gA0 = A  + (size_t)(bm * 128 + r0) * K + c0 * 8;
    const uint16_t* gA1 = A  + (size_t)(bm * 128 + r1) * K + c1 * 8;
    const uint16_t* gB0 = Wt + (size_t)(bn * 128 + r0) * K + c0 * 8;
    const uint16_t* gB1 = Wt + (size_t)(bn * 128 + r1) * K + c1 * 8;

    char* ldsA = (char*)lds;
    char* ldsB = (char*)lds + NPL * 8192;
    const int wb = wave * 1024;

    const int l15 = lane & 15, quad = lane >> 4;
    const int cpf = quad ^ ((l15 >> 1) & 3);
    const int aoff = ((wm * 64 + l15) * 4 + cpf) * 16;
    const int boff = ((wn * 64 + l15) * 4 + cpf) * 16;

    f32x4 accM[4][4], accC[4][4];
    #pragma unroll
    for (int mi = 0; mi < 4; ++mi)
        #pragma unroll
        for (int nj = 0; nj < 4; ++nj)
            #pragma unroll
            for (int r = 0; r < 4; ++r) { accM[mi][nj][r] = 0.f; if (CORR) accC[mi][nj][r] = 0.f; }

    for (int kk = 0; kk < K; kk += 32) {
        __syncthreads();
        #pragma unroll
        for (int p = 0; p < NPL; ++p) {
            GLOAD_LDS16(gA0 + (size_t)p * planeA, ldsA + p * 8192 + wb);
            GLOAD_LDS16(gA1 + (size_t)p * planeA, ldsA + p * 8192 + 4096 + wb);
            GLOAD_LDS16(gB0 + (size_t)p * planeB, ldsB + p * 8192 + wb);
            GLOAD_LDS16(gB1 + (size_t)p * planeB, ldsB + p * 8192 + 4096 + wb);
        }
        gA0 += 32; gA1 += 32; gB0 += 32; gB1 += 32;
        __syncthreads();

        vec8 a0[4], b0[4];
        #pragma unroll
        for (int i = 0; i < 4; ++i) {
            a0[i] = *(const vec8*)(ldsA + aoff + i * 1024);
            b0[i] = *(const vec8*)(ldsB + boff + i * 1024);
        }
        #pragma unroll
        for (int mi = 0; mi < 4; ++mi)
            #pragma unroll
            for (int nj = 0; nj < 4; ++nj)
                accM[mi][nj] = mfma16(a0[mi], b0[nj], accM[mi][nj]);

        if (CORR) {
            vec8 b1[4];
            #pragma unroll
            for (int i = 0; i < 4; ++i)
                b1[i] = *(const vec8*)(ldsB + 8192 + boff + i * 1024);
            #pragma unroll
            for (int mi = 0; mi < 4; ++mi)
                #pragma unroll
                for (int nj = 0; nj < 4; ++nj)
                    accC[mi][nj] = mfma16(a0[mi], b1[nj], accC[mi][nj]);
            vec8 a1[4];
            #pragma unroll
            for (int i = 0; i < 4; ++i)
                a1[i] = *(const vec8*)(ldsA + 8192 + aoff + i * 1024);
            #pragma unroll
            for (int mi = 0; mi < 4; ++mi)
                #pragma unroll
                for (int nj = 0; nj < 4; ++nj)
                    accC[mi][nj] = mfma16(a1[mi], b0[nj], accC[mi][nj]);
        }
    }

    if (CORR) {
        #pragma unroll
        for (int mi = 0; mi < 4; ++mi)
            #pragma unroll
            for (int nj = 0; nj < 4; ++nj)
                #pragma unroll
                for (int r = 0; r < 4; ++r)
                    accM[mi][nj][r] += accC[mi][nj][r] * (1.0f / 2048.0f);
    }

    const int colb = bn * 128 + wn * 64 + l15;
    const int rowb = bm * 128 + wm * 64 + quad * 4;
    float bz[4];
    #pragma unroll
    for (int nj = 0; nj < 4; ++nj) bz[nj] = bias[colb + nj * 16];

    #pragma unroll
    for (int mi = 0; mi < 4; ++mi)
        #pragma unroll
        for (int nj = 0; nj < 4; ++nj)
            #pragma unroll
            for (int r = 0; r < 4; ++r) {
                float v = accM[mi][nj][r] + bz[nj];
                if (RELU) v = fmaxf(v, 0.f);
                const size_t o = (size_t)(rowb + mi * 16 + r) * N + colb + nj * 16;
                if (OUT == 0) {
                    Cf[o] = v;
                } else if (OUT == 1) {
                    uint16_t hb, lb; split16(v, hb, lb);
                    C0[o] = hb; C1[o] = lb;
                } else {
                    C0[o] = f32_to_bf16(v);
                }
            }
}

// ---------------------------------------------------------------------------
// Weight prep (unchanged)
// ---------------------------------------------------------------------------
template<int MODE>
__global__ __launch_bounds__(256)
void prep_w(const float* __restrict__ W, uint16_t* __restrict__ out, int K, int N) {
    __shared__ float tile[32][33];
    const int tx = threadIdx.x & 31, ty = threadIdx.x >> 5;
    const int n0 = blockIdx.x * 32, k0 = blockIdx.y * 32;
    #pragma unroll
    for (int i = 0; i < 4; ++i)
        tile[ty + i * 8][tx] = W[(size_t)(k0 + ty + i * 8) * N + n0 + tx];
    __syncthreads();
    #pragma unroll
    for (int i = 0; i < 4; ++i) {
        float v = tile[tx][ty + i * 8];
        size_t o = (size_t)(n0 + ty + i * 8) * K + k0 + tx;
        if (MODE == 0) {
            uint16_t hb, lb; split16(v, hb, lb);
            out[o] = hb;
            out[o + (size_t)N * K] = lb;
        } else {
            out[o] = f32_to_bf16(v);
        }
    }
}

__global__ __launch_bounds__(256)
void split_x(const float* __restrict__ x, uint16_t* __restrict__ hi,
             uint16_t* __restrict__ lo, int n4) {
    int i = blockIdx.x * 256 + threadIdx.x;
    const int stride = gridDim.x * 256;
    for (; i < n4; i += stride) {
        float4 v = ((const float4*)x)[i];
        ushort4 h, l;
        split16(v.x, h.x, l.x); split16(v.y, h.y, l.y);
        split16(v.z, h.z, l.z); split16(v.w, h.w, l.w);
        ((ushort4*)hi)[i] = h;
        ((ushort4*)lo)[i] = l;
    }
}

// ---------------------------------------------------------------------------
// Codebook prep: f16 hi/lo planes [l][e][k][d] (native layout = B operand
// [N][K]) + cnorm.  One wave per codeword row.
// ---------------------------------------------------------------------------
__global__ __launch_bounds__(256)
void prep_cb2(const float* __restrict__ cb, uint16_t* __restrict__ cbh,
              uint16_t* __restrict__ cbl, float* __restrict__ cnorm) {
    const int t = threadIdx.x, wave = t >> 6, lane = t & 63;
    const int row = blockIdx.x * 4 + wave;       // 0..10239
    const float2 v = *(const float2*)(cb + (size_t)row * 128 + lane * 2);
    ushort2 h, l;
    split16(v.x, h.x, l.x); split16(v.y, h.y, l.y);
    *(ushort2*)(cbh + (size_t)row * 128 + lane * 2) = h;
    *(ushort2*)(cbl + (size_t)row * 128 + lane * 2) = l;
    const float s = wave_sum(v.x * v.x + v.y * v.y);
    if (lane == 0) cnorm[row] = s;
}

// ---------------------------------------------------------------------------
// Expert histogram -> offsets (single block); zero the scatter counters.
// ---------------------------------------------------------------------------
__global__ __launch_bounds__(256)
void hist_kernel(const int* __restrict__ labels, int* __restrict__ off,
                 int* __restrict__ cnt) {
    __shared__ int h[10];
    const int t = threadIdx.x;
    if (t < 10) h[t] = 0;
    __syncthreads();
    for (int i = t; i < 32768; i += 256) atomicAdd(&h[labels[i]], 1);
    __syncthreads();
    if (t == 0) {
        int a = 0;
        for (int e = 0; e < 10; ++e) { off[e] = a; a += h[e]; }
        off[10] = a;
    }
    if (t < 10) cnt[t] = 0;
}

// Block-aggregated scatter: perm[pos] = row, rows grouped by expert.
__global__ __launch_bounds__(256)
void scatter_kernel(const int* __restrict__ labels, const int* __restrict__ off,
                    int* __restrict__ cnt, int* __restrict__ perm) {
    __shared__ int h[10], base[10];
    const int t = threadIdx.x;
    const int r = blockIdx.x * 256 + t;
    if (t < 10) h[t] = 0;
    __syncthreads();
    const int e = labels[r];
    const int lr = atomicAdd(&h[e], 1);
    __syncthreads();
    if (t < 10) base[t] = (h[t] > 0) ? atomicAdd(&cnt[t], h[t]) : 0;
    __syncthreads();
    perm[off[e] + base[e] + lr] = r;
}

// Gather z rows into permuted residual buffer (f32 + f16 hi/lo planes).
__global__ __launch_bounds__(256)
void gather_kernel(const int* __restrict__ perm, const float* __restrict__ z,
                   float* __restrict__ resp, uint16_t* __restrict__ resph,
                   uint16_t* __restrict__ respl) {
    const int t = threadIdx.x, wave = t >> 6, lane = t & 63;
    const int p = blockIdx.x * 4 + wave;
    const int r = perm[p];
    const float2 v = *(const float2*)(z + (size_t)r * 128 + lane * 2);
    *(float2*)(resp + (size_t)p * 128 + lane * 2) = v;
    ushort2 h, l;
    split16(v.x, h.x, l.x); split16(v.y, h.y, l.y);
    *(ushort2*)(resph + (size_t)p * 128 + lane * 2) = h;
    *(ushort2*)(respl + (size_t)p * 128 + lane * 2) = l;
}

// ---------------------------------------------------------------------------
// Fused RQ level: 64 rows (one expert) x 256 codewords per block.
// score = cnorm - 2*dot  (rnorm is row-constant: drops out of argmin).
// dot via f16-split MFMA, 3 products. Then argmin + exact fp32 update.
// loss_l = (1+beta)*mean(res_new^2).
// ---------------------------------------------------------------------------
#define BETA_F 0.001f

template<bool LAST>
__global__ __launch_bounds__(256)
void rq_level(int l, const int* __restrict__ off, const int* __restrict__ perm,
              const float* __restrict__ cb, const uint16_t* __restrict__ cbh,
              const uint16_t* __restrict__ cbl, const float* __restrict__ cnorm,
              float* __restrict__ resp, uint16_t* __restrict__ resph,
              uint16_t* __restrict__ respl, const float* __restrict__ z,
              float* __restrict__ out_idx, float* __restrict__ out_xq,
              float* __restrict__ out_loss, uint16_t* __restrict__ xqbf) {
    __shared__ __align__(16) uint16_t Ah[2048], Al[2048];   // 64 rows x 32 halves
    __shared__ __align__(16) uint16_t Bh[8192], Bl[8192];   // 256 cols x 32 halves
    __shared__ float redv[64][4];
    __shared__ int   redk[64][4];
    __shared__ int   kwin[64];
    __shared__ float wl[4];
    __shared__ int   soff[11];

    const int t = threadIdx.x, lane = t & 63, wave = t >> 6;
    if (t < 11) soff[t] = off[t];
    __syncthreads();

    int e = -1, tile = 0, acc = 0;
    #pragma unroll
    for (int i = 0; i < 10; ++i) {
        const int nb = (soff[i + 1] - soff[i] + 63) >> 6;
        if ((int)blockIdx.x < acc + nb && e < 0) { e = i; tile = blockIdx.x - acc; }
        acc += nb;
    }
    if (e < 0) return;
    const int p0 = soff[e] + tile * 64;
    const int nrows = min(64, soff[e + 1] - p0);
    const int le = l * 10 + e;

    const int l15 = lane & 15, quad = lane >> 4;
    const int wn = wave;

    // ---- A staging source (1 chunk of 16B per thread per plane) ----
    const int ar = t >> 2;
    const int ac = (t & 3) ^ ((ar >> 1) & 3);
    const int arp = p0 + ((ar < nrows) ? ar : 0);
    const uint16_t* gAh = resph + (size_t)arp * 128 + ac * 8;
    const uint16_t* gAl = respl + (size_t)arp * 128 + ac * 8;
    const uint16_t* cbh_b = cbh + (size_t)le * 256 * 128;
    const uint16_t* cbl_b = cbl + (size_t)le * 256 * 128;

    f32x4 accM[4][4], accC[4][4];
    #pragma unroll
    for (int mi = 0; mi < 4; ++mi)
        #pragma unroll
        for (int nj = 0; nj < 4; ++nj)
            #pragma unroll
            for (int r = 0; r < 4; ++r) { accM[mi][nj][r] = 0.f; accC[mi][nj][r] = 0.f; }

    const int cpf = quad ^ ((l15 >> 1) & 3);

    for (int kc = 0; kc < 4; ++kc) {
        const int kk = kc * 32;
        __syncthreads();
        GLOAD_LDS16(gAh + kk, (char*)Ah + t * 16);
        GLOAD_LDS16(gAl + kk, (char*)Al + t * 16);
        #pragma unroll
        for (int rnd = 0; rnd < 4; ++rnd) {
            const int j = rnd * 256 + t;
            const int br = j >> 2;
            const int bc = (j & 3) ^ ((br >> 1) & 3);
            GLOAD_LDS16(cbh_b + (size_t)br * 128 + kk + bc * 8, (char*)Bh + j * 16);
            GLOAD_LDS16(cbl_b + (size_t)br * 128 + kk + bc * 8, (char*)Bl + j * 16);
        }
        __syncthreads();

        half8 ah[4], bh[4];
        #pragma unroll
        for (int i = 0; i < 4; ++i) {
            ah[i] = *(const half8*)((char*)Ah + ((i * 16 + l15) * 4 + cpf) * 16);
            bh[i] = *(const half8*)((char*)Bh + ((wn * 64 + i * 16 + l15) * 4 + cpf) * 16);
        }
        #pragma unroll
        for (int mi = 0; mi < 4; ++mi)
            #pragma unroll
            for (int nj = 0; nj < 4; ++nj)
                accM[mi][nj] = mfma16(ah[mi], bh[nj], accM[mi][nj]);

        half8 bl4[4];
        #pragma unroll
        for (int i = 0; i < 4; ++i)
            bl4[i] = *(const half8*)((char*)Bl + ((wn * 64 + i * 16 + l15) * 4 + cpf) * 16);
        #pragma unroll
        for (int mi = 0; mi < 4; ++mi)
            #pragma unroll
            for (int nj = 0; nj < 4; ++nj)
                accC[mi][nj] = mfma16(ah[mi], bl4[nj], accC[mi][nj]);

        half8 al4[4];
        #pragma unroll
        for (int i = 0; i < 4; ++i)
            al4[i] = *(const half8*)((char*)Al + ((i * 16 + l15) * 4 + cpf) * 16);
        #pragma unroll
        for (int mi = 0; mi < 4; ++mi)
            #pragma unroll
            for (int nj = 0; nj < 4; ++nj)
                accC[mi][nj] = mfma16(al4[mi], bh[nj], accC[mi][nj]);
    }

    // ---- scores + per-row argmin ----
    float cnv[4];
    #pragma unroll
    for (int nj = 0; nj < 4; ++nj)
        cnv[nj] = cnorm[le * 256 + wn * 64 + nj * 16 + l15];

    #pragma unroll
    for (int mi = 0; mi < 4; ++mi)
        #pragma unroll
        for (int r = 0; r < 4; ++r) {
            float bv = 1e30f; int bk = 0;
            #pragma unroll
            for (int nj = 0; nj < 4; ++nj) {
                const float d = cnv[nj] -
                    2.f * (accM[mi][nj][r] + accC[mi][nj][r] * (1.0f / 2048.0f));
                const int k = wn * 64 + nj * 16 + l15;
                if (d < bv || (d == bv && k < bk)) { bv = d; bk = k; }
            }
            #pragma unroll
            for (int o = 1; o < 16; o <<= 1) {
                const float ov = __shfl_xor(bv, o, 64);
                const int   ok = __shfl_xor(bk, o, 64);
                if (ov < bv || (ov == bv && ok < bk)) { bv = ov; bk = ok; }
            }
            const int row = mi * 16 + quad * 4 + r;
            if (l15 == 0) { redv[row][wn] = bv; redk[row][wn] = bk; }
        }
    __syncthreads();

    if (wave == 0) {
        const int row = lane;
        if (row < nrows) {
            float bv = redv[row][0]; int bk = redk[row][0];
            #pragma unroll
            for (int w = 1; w < 4; ++w) {
                const float ov = redv[row][w]; const int ok = redk[row][w];
                if (ov < bv || (ov == bv && ok < bk)) { bv = ov; bk = ok; }
            }
            kwin[row] = bk;
            out_idx[(size_t)perm[p0 + row] * 4 + l] = (float)bk;
        }
    }
    __syncthreads();

    // ---- exact fp32 residual update, loss, (LAST: x_q outputs) ----
    float lossw = 0.f;
    for (int i = 0; i < 16; ++i) {
        const int row = wave * 16 + i;
        if (row < nrows) {
            const int p = p0 + row;
            const int k = kwin[row];
            const float2 q2 = *(const float2*)(cb + ((size_t)le * 256 + k) * 128 + lane * 2);
            float2 r2 = *(float2*)(resp + (size_t)p * 128 + lane * 2);
            const float n0 = r2.x - q2.x, n1 = r2.y - q2.y;
            *(float2*)(resp + (size_t)p * 128 + lane * 2) = make_float2(n0, n1);
            if (!LAST) {
                ushort2 h, lo;
                split16(n0, h.x, lo.x); split16(n1, h.y, lo.y);
                *(ushort2*)(resph + (size_t)p * 128 + lane * 2) = h;
                *(ushort2*)(respl + (size_t)p * 128 + lane * 2) = lo;
            }
            lossw += wave_sum(n0 * n0 + n1 * n1);
            if (LAST) {
                const int orig = perm[p];
                const float2 z2 = *(const float2*)(z + (size_t)orig * 128 + lane * 2);
                const float xq0 = z2.x - n0, xq1 = z2.y - n1;
                out_xq[(size_t)orig * 128 + lane * 2]     = xq0;
                out_xq[(size_t)orig * 128 + lane * 2 + 1] = xq1;
                ushort2 xb; xb.x = f32_to_bf16(xq0); xb.y = f32_to_bf16(xq1);
                *(ushort2*)(xqbf + (size_t)orig * 128 + lane * 2) = xb;
            }
        }
    }
    if (lane == 0) wl[wave] = lossw;
    __syncthreads();
    if (t == 0)
        atomicAdd(out_loss, (wl[0] + wl[1] + wl[2] + wl[3]) *
                            ((1.0f + BETA_F) / (32768.0f * 128.0f)));
}

// ---------------------------------------------------------------------------

extern "C" void kernel_launch(void* const* d_in, const int* in_sizes, int n_in,
                              void* d_out, int out_size, void* d_ws, size_t ws_size,
                              hipStream_t stream) {
    const float* x      = (const float*)d_in[0];
    const int*   labels = (const int*)d_in[1];
    const float* ew[4]  = {(const float*)d_in[2], (const float*)d_in[4],
                           (const float*)d_in[6], (const float*)d_in[8]};
    const float* eb[4]  = {(const float*)d_in[3], (const float*)d_in[5],
                           (const float*)d_in[7], (const float*)d_in[9]};
    const float* dw[4]  = {(const float*)d_in[10], (const float*)d_in[12],
                           (const float*)d_in[14], (const float*)d_in[16]};
    const float* db[4]  = {(const float*)d_in[11], (const float*)d_in[13],
                           (const float*)d_in[15], (const float*)d_in[17]};
    const float* cb     = (const float*)d_in[18];

    float* out = (float*)d_out;
    const size_t LOSS_OFF = 25165824;
    const size_t IDX_OFF  = 25165825;
    const size_t XQ_OFF   = 25296897;

    // ---- workspace ----
    char* W = (char*)d_ws;
    size_t off_b = 0;
    auto alloc = [&](size_t bytes) { char* p = W + off_b; off_b += (bytes + 255) & ~(size_t)255; return p; };
    char*     region1 = alloc(134217728);          // 128 MiB (enc h1/h3, RQ bufs, dec d0/d2)
    char*     region2 = alloc(67108864);           // 64 MiB  (enc x/h2, dec d1)
    float*    z       = (float*)alloc(32768ull * 128 * 4);
    uint16_t* xqbf    = (uint16_t*)alloc(32768ull * 128 * 2);
    uint16_t* wtE0 = (uint16_t*)alloc(2ull *  768 * 2048 * 2);
    uint16_t* wtE1 = (uint16_t*)alloc(2ull * 2048 * 1024 * 2);
    uint16_t* wtE2 = (uint16_t*)alloc(2ull * 1024 *  512 * 2);
    uint16_t* wtE3 = (uint16_t*)alloc(2ull *  512 *  128 * 2);
    uint16_t* wtD0 = (uint16_t*)alloc(128ull  *  512 * 2);
    uint16_t* wtD1 = (uint16_t*)alloc(512ull  * 1024 * 2);
    uint16_t* wtD2 = (uint16_t*)alloc(1024ull * 2048 * 2);
    uint16_t* wtD3 = (uint16_t*)alloc(2048ull *  768 * 2);

    // RQ-phase buffers live inside region1 (free between encoder and decoder)
    char* r1 = region1;
    float*    resp  = (float*)r1;                      r1 += 32768ull * 128 * 4;
    uint16_t* resph = (uint16_t*)r1;                   r1 += 32768ull * 128 * 2;
    uint16_t* respl = (uint16_t*)r1;                   r1 += 32768ull * 128 * 2;
    uint16_t* cbh   = (uint16_t*)r1;                   r1 += 4ull * 10 * 256 * 128 * 2;
    uint16_t* cbl   = (uint16_t*)r1;                   r1 += 4ull * 10 * 256 * 128 * 2;
    float*    cnorm = (float*)r1;                      r1 += 4ull * 10 * 256 * 4;
    int*      permv = (int*)r1;                        r1 += 32768ull * 4;
    int*      eoff  = (int*)r1;                        r1 += 16 * 4;
    int*      ecnt  = (int*)r1;                        r1 += 16 * 4;

    dim3 blk(256);

    // ---- weight prep ----
    prep_w<0><<<dim3(2048/32,  768/32), blk, 0, stream>>>(ew[0], wtE0,  768, 2048);
    prep_w<0><<<dim3(1024/32, 2048/32), blk, 0, stream>>>(ew[1], wtE1, 2048, 1024);
    prep_w<0><<<dim3( 512/32, 1024/32), blk, 0, stream>>>(ew[2], wtE2, 1024,  512);
    prep_w<0><<<dim3( 128/32,  512/32), blk, 0, stream>>>(ew[3], wtE3,  512,  128);
    prep_w<1><<<dim3( 512/32,  128/32), blk, 0, stream>>>(dw[0], wtD0,  128,  512);
    prep_w<1><<<dim3(1024/32,  512/32), blk, 0, stream>>>(dw[1], wtD1,  512, 1024);
    prep_w<1><<<dim3(2048/32, 1024/32), blk, 0, stream>>>(dw[2], wtD2, 1024, 2048);
    prep_w<1><<<dim3( 768/32, 2048/32), blk, 0, stream>>>(dw[3], wtD3, 2048,  768);

    // ---- encoder in two M-halves ----
    const int MH = 16384;
    for (int half = 0; half < 2; ++half) {
        const float* xh = x + (size_t)half * MH * 768;
        uint16_t* xpl = (uint16_t*)region2;
        split_x<<<1024, blk, 0, stream>>>(xh, xpl, xpl + (size_t)MH * 768, MH * 768 / 4);

        uint16_t* h1 = (uint16_t*)region1;
        gemm_mfma<2, true, true, true, 1><<<dim3(16, 128), blk, 0, stream>>>(
            xpl, wtE0, eb[0], nullptr, h1, h1 + (size_t)MH * 2048, MH, 768, 2048);

        uint16_t* h2 = (uint16_t*)region2;
        gemm_mfma<2, true, true, true, 1><<<dim3(8, 128), blk, 0, stream>>>(
            h1, wtE1, eb[1], nullptr, h2, h2 + (size_t)MH * 1024, MH, 2048, 1024);

        uint16_t* h3 = (uint16_t*)region1;
        gemm_mfma<2, true, true, true, 1><<<dim3(4, 128), blk, 0, stream>>>(
            h2, wtE2, eb[2], nullptr, h3, h3 + (size_t)MH * 512, MH, 1024, 512);

        gemm_mfma<2, true, true, false, 0><<<dim3(1, 128), blk, 0, stream>>>(
            h3, wtE3, eb[3], z + (size_t)half * MH * 128, nullptr, nullptr, MH, 512, 128);
    }

    // ---- RQ prep (region1 now free) ----
    prep_cb2<<<2560, blk, 0, stream>>>(cb, cbh, cbl, cnorm);
    hist_kernel<<<1, blk, 0, stream>>>(labels, eoff, ecnt);
    scatter_kernel<<<128, blk, 0, stream>>>(labels, eoff, ecnt, permv);
    gather_kernel<<<8192, blk, 0, stream>>>(permv, z, resp, resph, respl);
    hipMemsetAsync((char*)d_out + LOSS_OFF * 4, 0, 4, stream);

    // ---- 4 RQ levels ----
    rq_level<false><<<522, blk, 0, stream>>>(0, eoff, permv, cb, cbh, cbl, cnorm,
        resp, resph, respl, z, out + IDX_OFF, out + XQ_OFF, out + LOSS_OFF, xqbf);
    rq_level<false><<<522, blk, 0, stream>>>(1, eoff, permv, cb, cbh, cbl, cnorm,
        resp, resph, respl, z, out + IDX_OFF, out + XQ_OFF, out + LOSS_OFF, xqbf);
    rq_level<false><<<522, blk, 0, stream>>>(2, eoff, permv, cb, cbh, cbl, cnorm,
        resp, resph, respl, z, out + IDX_OFF, out + XQ_OFF, out + LOSS_OFF, xqbf);
    rq_level<true ><<<522, blk, 0, stream>>>(3, eoff, permv, cb, cbh, cbl, cnorm,
        resp, resph, respl, z, out + IDX_OFF, out + XQ_OFF, out + LOSS_OFF, xqbf);

    // ---- decoder, bf16 ----
    const int M = 32768;
    uint16_t* d0 = (uint16_t*)region1;
    uint16_t* d1 = (uint16_t*)region2;
    uint16_t* d2 = (uint16_t*)region1;
    gemm_mfma<1, false, false, true, 2><<<dim3(4, 256), blk, 0, stream>>>(
        xqbf, wtD0, db[0], nullptr, d0, nullptr, M, 128, 512);
    gemm_mfma<1, false, false, true, 2><<<dim3(8, 256), blk, 0, stream>>>(
        d0, wtD1, db[1], nullptr, d1, nullptr, M, 512, 1024);
    gemm_mfma<1, false, false, true, 2><<<dim3(16, 256), blk, 0, stream>>>(
        d1, wtD2, db[2], nullptr, d2, nullptr, M, 1024, 2048);
    gemm_mfma<1, false, false, false, 0><<<dim3(6, 256), blk, 0, stream>>>(
        d2, wtD3, db[3], out, nullptr, nullptr, M, 2048, 768);
}